// Round 2
// baseline (50.942 us; speedup 1.0000x reference)
//
#include <hip/hip_runtime.h>

#define DD 128          // embedding dim
#define KK 64           // neighbors
#define NT 256          // threads per block
#define NG 8            // groups of 32 lanes
#define KPG (KK / NG)   // k's per group = 8

__global__ __launch_bounds__(NT, 4) void ga_kernel(
    const int*   __restrict__ node_ids,      // [B3]
    const int*   __restrict__ neighbor_ids,  // [B3*K]
    const int*   __restrict__ neighbor_mask, // [B3*K]
    const float* __restrict__ emb,           // [V*D]
    const float* __restrict__ gamma,
    const float* __restrict__ beta,
    float*       __restrict__ out,           // [B3*D]
    int B3)
{
    __shared__ float red[NG][DD];   // per-group partial att_out (4 KB)
    __shared__ float node_lds[DD];
    __shared__ float xbuf[DD];
    __shared__ int   nid_s[KK];
    __shared__ int   msk_s[KK];
    __shared__ float mu_s, rs_s;

    const int blk = blockIdx.x;
    if (blk >= B3) return;
    const int t = threadIdx.x;
    const int g = t >> 5;     // group 0..7
    const int c = t & 31;     // 16B column chunk 0..31

    // stage indices + mask (tiny, broadcast later from LDS)
    if (t < KK) {
        nid_s[t] = neighbor_ids[(size_t)blk * KK + t];
        msk_s[t] = neighbor_mask[(size_t)blk * KK + t];
    }

    // node row: every group loads the same 32 float4s (L1 broadcast)
    const long long nodeid = (long long)node_ids[blk];
    const float4 nv = ((const float4*)(emb + (size_t)nodeid * DD))[c];
    if (g == 0) ((float4*)node_lds)[c] = nv;
    __syncthreads();

    // fused gather + QK^T dot + incremental PV accumulate
    float4 acc = make_float4(0.f, 0.f, 0.f, 0.f);
    #pragma unroll
    for (int j = 0; j < KPG; ++j) {
        const int k = g * KPG + j;
        const int m = msk_s[k];
        float4 v = make_float4(0.f, 0.f, 0.f, 0.f);
        if (m) {  // skip global load entirely for masked-out neighbors
            v = ((const float4*)(emb + (size_t)nid_s[k] * DD))[c];
        }
        float p = v.x * nv.x + v.y * nv.y + v.z * nv.z + v.w * nv.w;
        // butterfly reduce across the 32-lane half-wave (all lanes get sum)
        p += __shfl_xor(p, 16);
        p += __shfl_xor(p, 8);
        p += __shfl_xor(p, 4);
        p += __shfl_xor(p, 2);
        p += __shfl_xor(p, 1);
        const float att = p / 15.0f;
        acc.x += att * v.x;
        acc.y += att * v.y;
        acc.z += att * v.z;
        acc.w += att * v.w;
    }
    ((float4*)red[g])[c] = acc;
    __syncthreads();

    // combine the 8 group partials -> x = node + att_out
    if (t < DD) {
        float s = 0.f;
        #pragma unroll
        for (int gg = 0; gg < NG; ++gg) s += red[gg][t];
        xbuf[t] = node_lds[t] + s;
    }
    __syncthreads();

    // layernorm over 128 values: one wave does the reductions
    if (t < 64) {
        const float x0 = xbuf[t], x1 = xbuf[t + 64];
        float s = x0 + x1;
        s += __shfl_xor(s, 32); s += __shfl_xor(s, 16); s += __shfl_xor(s, 8);
        s += __shfl_xor(s, 4);  s += __shfl_xor(s, 2);  s += __shfl_xor(s, 1);
        const float mu = s * (1.0f / 128.0f);
        const float d0 = x0 - mu, d1 = x1 - mu;
        float v2 = d0 * d0 + d1 * d1;
        v2 += __shfl_xor(v2, 32); v2 += __shfl_xor(v2, 16); v2 += __shfl_xor(v2, 8);
        v2 += __shfl_xor(v2, 4);  v2 += __shfl_xor(v2, 2);  v2 += __shfl_xor(v2, 1);
        if (t == 0) {
            mu_s = mu;
            rs_s = rsqrtf(v2 * (1.0f / 128.0f) + 1e-5f);
        }
    }
    __syncthreads();

    if (t < DD) {
        const float x = xbuf[t];
        out[(size_t)blk * DD + t] = (x - mu_s) * rs_s * gamma[t] + beta[t];
    }
}

extern "C" void kernel_launch(void* const* d_in, const int* in_sizes, int n_in,
                              void* d_out, int out_size, void* d_ws, size_t ws_size,
                              hipStream_t stream) {
    const int*   node_ids      = (const int*)  d_in[0];
    const int*   neighbor_ids  = (const int*)  d_in[1];
    const int*   neighbor_mask = (const int*)  d_in[2];
    const float* emb           = (const float*)d_in[3];
    const float* gamma         = (const float*)d_in[4];
    const float* beta          = (const float*)d_in[5];
    float*       out           = (float*)d_out;

    const int B3 = in_sizes[0];  // B*3 = 12288

    ga_kernel<<<B3, NT, 0, stream>>>(node_ids, neighbor_ids, neighbor_mask,
                                     emb, gamma, beta, out, B3);
}

// Round 3
// 39.972 us; speedup vs baseline: 1.2744x; 1.2744x over previous
//
#include <hip/hip_runtime.h>

#define DD 128          // embedding dim
#define KK 64           // neighbors
#define NT 256          // threads per block
#define NG 8            // groups of 32 lanes
#define KPG (KK / NG)   // k's per group = 8

__global__ __launch_bounds__(NT, 8) void ga_kernel(
    const int*   __restrict__ node_ids,      // [B3]
    const int*   __restrict__ neighbor_ids,  // [B3*K]
    const int*   __restrict__ neighbor_mask, // [B3*K]
    const float* __restrict__ emb,           // [V*D]
    const float* __restrict__ gamma,
    const float* __restrict__ beta,
    float*       __restrict__ out,           // [B3*D]
    int B3)
{
    __shared__ float red[NG][DD];   // per-group partial att_out (4 KB)
    __shared__ float node_lds[DD];
    __shared__ int   nid_s[KK];
    __shared__ int   msk_s[KK];

    const int blk = blockIdx.x;
    if (blk >= B3) return;
    const int t = threadIdx.x;
    const int g = t >> 5;     // group 0..7
    const int c = t & 31;     // 16B column chunk 0..31

    // stage indices + mask
    if (t < KK) {
        nid_s[t] = neighbor_ids[(size_t)blk * KK + t];
        msk_s[t] = neighbor_mask[(size_t)blk * KK + t];
    }

    // node row: every group loads the same 32 float4s (L1 broadcast)
    const long long nodeid = (long long)node_ids[blk];
    const float4 nv = ((const float4*)(emb + (size_t)nodeid * DD))[c];
    if (g == 0) ((float4*)node_lds)[c] = nv;
    __syncthreads();

    // ---- phase 1: issue ALL gathers (8 outstanding loads per wave) ----
    float4 v[KPG];
    #pragma unroll
    for (int j = 0; j < KPG; ++j) {
        const int k = g * KPG + j;
        v[j] = make_float4(0.f, 0.f, 0.f, 0.f);
        if (msk_s[k]) {   // skip global load entirely for masked-out neighbors
            v[j] = ((const float4*)(emb + (size_t)nid_s[k] * DD))[c];
        }
    }

    // ---- phase 2: 8 independent dot/reduce/accumulate chains ----
    float4 acc = make_float4(0.f, 0.f, 0.f, 0.f);
    #pragma unroll
    for (int j = 0; j < KPG; ++j) {
        float p = v[j].x * nv.x + v[j].y * nv.y + v[j].z * nv.z + v[j].w * nv.w;
        p += __shfl_xor(p, 16);
        p += __shfl_xor(p, 8);
        p += __shfl_xor(p, 4);
        p += __shfl_xor(p, 2);
        p += __shfl_xor(p, 1);
        const float att = p * (1.0f / 15.0f);
        acc.x += att * v[j].x;
        acc.y += att * v[j].y;
        acc.z += att * v[j].z;
        acc.w += att * v[j].w;
    }
    ((float4*)red[g])[c] = acc;
    __syncthreads();

    // ---- fused epilogue: combine partials + layernorm + store (wave 0) ----
    if (t < 64) {
        float x0 = node_lds[t], x1 = node_lds[t + 64];
        #pragma unroll
        for (int gg = 0; gg < NG; ++gg) {
            x0 += red[gg][t];
            x1 += red[gg][t + 64];
        }
        float s = x0 + x1;
        s += __shfl_xor(s, 32); s += __shfl_xor(s, 16); s += __shfl_xor(s, 8);
        s += __shfl_xor(s, 4);  s += __shfl_xor(s, 2);  s += __shfl_xor(s, 1);
        const float mu = s * (1.0f / 128.0f);
        const float d0 = x0 - mu, d1 = x1 - mu;
        float v2 = d0 * d0 + d1 * d1;
        v2 += __shfl_xor(v2, 32); v2 += __shfl_xor(v2, 16); v2 += __shfl_xor(v2, 8);
        v2 += __shfl_xor(v2, 4);  v2 += __shfl_xor(v2, 2);  v2 += __shfl_xor(v2, 1);
        const float rs = rsqrtf(v2 * (1.0f / 128.0f) + 1e-5f);
        const size_t ob = (size_t)blk * DD;
        out[ob + t]      = d0 * rs * gamma[t]      + beta[t];
        out[ob + t + 64] = d1 * rs * gamma[t + 64] + beta[t + 64];
    }
}

extern "C" void kernel_launch(void* const* d_in, const int* in_sizes, int n_in,
                              void* d_out, int out_size, void* d_ws, size_t ws_size,
                              hipStream_t stream) {
    const int*   node_ids      = (const int*)  d_in[0];
    const int*   neighbor_ids  = (const int*)  d_in[1];
    const int*   neighbor_mask = (const int*)  d_in[2];
    const float* emb           = (const float*)d_in[3];
    const float* gamma         = (const float*)d_in[4];
    const float* beta          = (const float*)d_in[5];
    float*       out           = (float*)d_out;

    const int B3 = in_sizes[0];  // B*3 = 12288

    ga_kernel<<<B3, NT, 0, stream>>>(node_ids, neighbor_ids, neighbor_mask,
                                     emb, gamma, beta, out, B3);
}